// Round 9
// baseline (234.409 us; speedup 1.0000x reference)
//
#include <hip/hip_runtime.h>
#include <stdint.h>

typedef unsigned long long ull;

#define NUM_CLASSES 21
#define NFG 20
#define TOPK 200
#define KPRE 256
#define BS 256                   // 4 waves
#define NV 35                    // ceil(8732/256)
#define CONF_TH 0.01f
#define NMS_TH 0.45f
#define VAR0 0.1f
#define VAR1 0.2f
#define BITS_CONF 0x3C23D70Au    // __float_as_uint(0.01f)
#define BITS_ONE1 0x3F800001u    // just above 1.0f (softmax <= 1)

// Fused kernel with a MANUAL grid barrier (cooperative launch fails under
// graph capture). Residency proof: 640 blocks, ~18KB LDS, ~52 VGPR, 4 waves
// => 8 blocks/CU * 256 CU = 2048 capacity >> 640, so all blocks co-resident
// and the spin cannot deadlock.
// Phase 1: block (b,ci) computes softmax (mx, sum-exp) for rows
// [ci*437, ...) of image b -- each row exactly ONCE grid-wide (round 7 did
// it 20x = ~100us of redundant expf) -- and stores float2 to ws.
// Barrier. Phase 2: score = expf(x[cls]-mx)/s (bit-identical op order to
// the passing rounds), then the round-7 NMS pipeline.
__global__ __launch_bounds__(BS) void fused_nms_kernel(
    const float* __restrict__ conf, const float* __restrict__ loc,
    const float* __restrict__ prior, float* __restrict__ out,
    float2* __restrict__ msum, unsigned int* __restrict__ bar,
    int B, int P, int nblk) {

    __shared__ ull arr[2 * KPRE];        // 4 KB
    __shared__ float4 sbox[KPRE];        // 4 KB
    __shared__ float sarea[KPRE];        // 1 KB
    __shared__ ull smask[4][KPRE];       // 8 KB, [tile][row]: conflict-free
    __shared__ int wsum[2][4][3];
    __shared__ int s_cnt;
    __shared__ ull kept[4];
    __shared__ int s_chg[2];

    const int t = threadIdx.x;
    const int lane = t & 63;
    const int wid = t >> 6;              // 0..3
    const ull lmask_lt = (1ULL << lane) - 1ULL;

    // XCD swizzle: image b's 20 blocks land on XCD b%8 (perf-only heuristic;
    // correctness comes from the device-scope fences below)
    int pair;
    {
        int blk = blockIdx.x;
        if ((B & 7) == 0) {
            int x = blk & 7;
            int g = blk >> 3;
            int cls_i = g % NFG;
            int bhi = g / NFG;
            pair = (x + (bhi << 3)) * NFG + cls_i;
        } else {
            pair = blk;
        }
    }
    const int b = pair / NFG;
    const int ci = pair - b * NFG;       // 0..19; class = ci+1
    const int cls = ci + 1;

    if (t == 0) { s_cnt = 0; s_chg[0] = 0; s_chg[1] = 0; }

    // ---- Phase 1: per-row (mx, sum_exp), each (b,p) exactly once ----
    {
        const int rows = (P + NFG - 1) / NFG;          // 437
        const int pstart = ci * rows;
        const int pend = min(pstart + rows, P);
        const float* cbase = conf + (size_t)b * P * NUM_CLASSES;
        float2* ms = msum + (size_t)b * P;
        for (int p = pstart + t; p < pend; p += BS) {
            const float* row = cbase + (size_t)p * NUM_CLASSES;
            float x[NUM_CLASSES];
#pragma unroll
            for (int j = 0; j < NUM_CLASSES; ++j) x[j] = row[j];
            float mx = x[0];
#pragma unroll
            for (int j = 1; j < NUM_CLASSES; ++j) mx = fmaxf(mx, x[j]);
            float s = 0.f;
#pragma unroll
            for (int j = 0; j < NUM_CLASSES; ++j)     // ascending j: match ref ulps
                s += expf(x[j] - mx);
            ms[p] = make_float2(mx, s);
        }
    }
    // ---- manual grid barrier ----
    __syncthreads();                      // drains this block's stores (vmcnt 0)
    if (t == 0) {
        __threadfence();                  // release: writeback to coherence point
        __hip_atomic_fetch_add(bar, 1u, __ATOMIC_ACQ_REL, __HIP_MEMORY_SCOPE_AGENT);
        while (__hip_atomic_load(bar, __ATOMIC_ACQUIRE, __HIP_MEMORY_SCOPE_AGENT)
               < (unsigned int)nblk) {
            __builtin_amdgcn_s_sleep(2);
        }
        __threadfence();                  // acquire: invalidate stale cached lines
    }
    __syncthreads();

    // ---- Phase 2A: this class's scores into registers ----
    const float2* ms = msum + (size_t)b * P;
    const float* cbase = conf + (size_t)b * P * NUM_CLASSES;
    unsigned int ubits[NV];
#pragma unroll
    for (int i = 0; i < NV; ++i) {
        int p = (i << 8) + t;
        unsigned int u = 0u;
        if (p < P) {
            float2 m2 = ms[p];
            float xc = expf(cbase[(size_t)p * NUM_CLASSES + cls] - m2.x);
            u = __float_as_uint(xc / m2.y);   // identical expr to phase-1 path
        }
        ubits[i] = u;
    }

    // ---- B: largest T in [0.01,1] with count(bits>=T) >= 256; 2 bits/iter ----
    unsigned int lo = BITS_CONF, hi = BITS_ONE1;
    int it = 0;
    while (hi - lo > 1u) {
        unsigned int d = hi - lo;
        unsigned int m1, m2, m3;
        if (d >= 4u) { unsigned int q = d >> 2; m1 = lo + q; m2 = lo + 2 * q; m3 = lo + 3 * q; }
        else { m1 = m2 = m3 = lo + (d >> 1); }
        int c1 = 0, c2 = 0, c3 = 0;
#pragma unroll
        for (int i = 0; i < NV; ++i) {
            unsigned int u = ubits[i];
            c1 += (u >= m1) ? 1 : 0;
            c2 += (u >= m2) ? 1 : 0;
            c3 += (u >= m3) ? 1 : 0;
        }
#pragma unroll
        for (int off = 32; off > 0; off >>= 1) {
            c1 += __shfl_down(c1, off);
            c2 += __shfl_down(c2, off);
            c3 += __shfl_down(c3, off);
        }
        if (lane == 0) {
            wsum[it & 1][wid][0] = c1; wsum[it & 1][wid][1] = c2; wsum[it & 1][wid][2] = c3;
        }
        __syncthreads();
        int t1 = 0, t2 = 0, t3 = 0;
#pragma unroll
        for (int w = 0; w < 4; ++w) {
            t1 += wsum[it & 1][w][0]; t2 += wsum[it & 1][w][1]; t3 += wsum[it & 1][w][2];
        }
        if (t3 >= KPRE) lo = m3;
        else if (t2 >= KPRE) { lo = m2; hi = m3; }
        else if (t1 >= KPRE) { lo = m1; hi = m2; }
        else hi = m1;
        ++it;
    }
    const unsigned int T = lo;

    // ---- C: ballot-compaction gather (cap 512) ----
    int wtot = 0;
#pragma unroll
    for (int i = 0; i < NV; ++i) {
        int p = (i << 8) + t;
        bool pred = (p < P) && (ubits[i] >= T);
        wtot += __popcll(__ballot(pred));
    }
    int wbase = 0;
    if (lane == 0) wbase = atomicAdd(&s_cnt, wtot);
    wbase = __shfl(wbase, 0);
    int run = wbase;
#pragma unroll
    for (int i = 0; i < NV; ++i) {
        int p = (i << 8) + t;
        bool pred = (p < P) && (ubits[i] >= T);
        ull bal = __ballot(pred);
        if (pred) {
            int slot = run + __popcll(bal & lmask_lt);
            if (slot < 2 * KPRE)
                arr[slot] = ((ull)ubits[i] << 32) | (unsigned int)(~p);
        }
        run += __popcll(bal);
    }
    __syncthreads();
    const int nval = min(s_cnt, 2 * KPRE);
    for (int e = t; e < 2 * KPRE; e += KPRE)
        if (e >= nval) arr[e] = 0ULL;
    __syncthreads();

    // ---- D: sort desc; key=(bits<<32)|~idx => value desc, index asc (JAX) ----
    ull key;
    if (nval <= KPRE) {
        key = arr[t];
        for (int kk = 2; kk <= KPRE; kk <<= 1) {
            for (int j = kk >> 1; j > 0; j >>= 1) {
                bool dirDesc = ((t & kk) == 0);
                ull other;
                if (j >= 64) {
                    arr[t] = key;
                    __syncthreads();
                    other = arr[t ^ j];
                    __syncthreads();
                } else {
                    other = __shfl_xor(key, j);
                }
                bool amLow = ((t & j) == 0);
                ull mx = (key > other) ? key : other;
                ull mn = (key > other) ? other : key;
                key = (dirDesc == amLow) ? mx : mn;
            }
        }
    } else {
        for (int kk = 2; kk <= 2 * KPRE; kk <<= 1) {
            for (int j = kk >> 1; j > 0; j >>= 1) {
                for (int e = t; e < 2 * KPRE; e += KPRE) {
                    int ixj = e ^ j;
                    if (ixj > e) {
                        ull a = arr[e], bb = arr[ixj];
                        bool up = ((e & kk) == 0);
                        if (up ? (a < bb) : (a > bb)) { arr[e] = bb; arr[ixj] = a; }
                    }
                }
                __syncthreads();
            }
        }
        key = arr[t];
    }

    // ---- E: decode candidate t ----
    float v = __uint_as_float((unsigned int)(key >> 32));
    int idx = (int)(~(unsigned int)(key & 0xFFFFFFFFu));
    if (idx < 0 || idx >= P) { idx = 0; v = 0.f; }
    const float4 lv = *(const float4*)(loc + ((size_t)b * P + idx) * 4);
    const float4 pv = *(const float4*)(prior + (size_t)idx * 4);
    float cx = pv.x + (lv.x * VAR0) * pv.z;
    float cy = pv.y + (lv.y * VAR0) * pv.w;
    float w = pv.z * expf(lv.z * VAR1);
    float h = pv.w * expf(lv.w * VAR1);
    float x1 = cx - w * 0.5f;
    float y1 = cy - h * 0.5f;
    float x2 = x1 + w;
    float y2 = y1 + h;
    float myarea = fmaxf(x2 - x1, 0.f) * fmaxf(y2 - y1, 0.f);
    sbox[t] = make_float4(x1, y1, x2, y2);
    sarea[t] = myarea;
    __syncthreads();

    // ---- F1: suppression masks, balanced (<=3 tiles/wave), broadcast g reads,
    // gated exact-IEEE div ----
#pragma unroll
    for (int k = 0; k < 3; ++k) {
        int tid = wid + (k << 2);
        if (tid < 10) {
            int rblk, tb;
            if (tid >= 6)      { rblk = 3; tb = tid - 6; }
            else if (tid >= 3) { rblk = 2; tb = tid - 3; }
            else if (tid >= 1) { rblk = 1; tb = tid - 1; }
            else               { rblk = 0; tb = 0; }
            int r = (rblk << 6) + lane;
            float4 rb = sbox[r];
            float ra = sarea[r];
            ull mm = 0ULL;
            for (int ii = 0; ii < 64; ++ii) {
                int g = (tb << 6) + ii;
                float4 gb = sbox[g];     // lane-uniform addr => LDS broadcast
                float lx = fmaxf(gb.x, rb.x), ly = fmaxf(gb.y, rb.y);
                float rx = fminf(gb.z, rb.z), ry = fminf(gb.w, rb.w);
                float inter = fmaxf(rx - lx, 0.f) * fmaxf(ry - ly, 0.f);
                bool s = false;
                if (inter > 0.f) {       // skip exact div for disjoint pairs
                    float uni = sarea[g] + ra - inter;
                    s = (inter / fmaxf(uni, 1e-9f)) > NMS_TH;
                }
                mm |= ((ull)(s ? 1u : 0u)) << ii;
            }
            smask[tb][r] = mm;
        }
    }
    __syncthreads();

    // ---- F2: Jacobi fixed-point (converges to exact sequential NMS) ----
    ull m0 = smask[0][t];
    ull m1 = (wid >= 1) ? smask[1][t] : 0ULL;
    ull m2 = (wid >= 2) ? smask[2][t] : 0ULL;
    ull m3 = (wid >= 3) ? smask[3][t] : 0ULL;
    if (wid == 0)      { m0 &= lmask_lt; m1 = 0; m2 = 0; m3 = 0; }
    else if (wid == 1) { m1 &= lmask_lt; m2 = 0; m3 = 0; }
    else if (wid == 2) { m2 &= lmask_lt; m3 = 0; }
    else               { m3 &= lmask_lt; }
    int valid = (v > CONF_TH) ? 1 : 0;
    int alive = valid;
    {
        ull km = __ballot(valid != 0);
        if (lane == 0) kept[wid] = km;
    }
    __syncthreads();
    for (int iter = 0; iter < KPRE; ++iter) {
        ull K0 = kept[0], K1 = kept[1], K2 = kept[2], K3 = kept[3];
        __syncthreads();
        ull dead = (m0 & K0) | (m1 & K1) | (m2 & K2) | (m3 & K3);
        alive = (valid && dead == 0ULL) ? 1 : 0;
        ull km = __ballot(alive != 0);
        ull oldk = (wid == 0) ? K0 : (wid == 1) ? K1 : (wid == 2) ? K2 : K3;
        if (lane == 0 && km != oldk) { kept[wid] = km; s_chg[iter & 1] = 1; }
        if (t == 0) s_chg[(iter & 1) ^ 1] = 0;
        __syncthreads();
        if (s_chg[iter & 1] == 0) break;
    }

    // ---- G: rank via popcounts, write kept rows + zero-fill ----
    {
        ull K0 = kept[0], K1 = kept[1], K2 = kept[2], K3 = kept[3];
        int rank = 0;
        if (wid > 0) rank += __popcll(K0);
        if (wid > 1) rank += __popcll(K1);
        if (wid > 2) rank += __popcll(K2);
        ull ownk = (wid == 0) ? K0 : (wid == 1) ? K1 : (wid == 2) ? K2 : K3;
        rank += __popcll(ownk & lmask_lt);
        int total = __popcll(K0) + __popcll(K1) + __popcll(K2) + __popcll(K3);

        float* orow = out + (size_t)pair * TOPK * 5;
        if (alive && rank < TOPK) {
            float* o = orow + rank * 5;
            o[0] = v; o[1] = x1; o[2] = y1; o[3] = x2; o[4] = y2;
        }
        if (t < TOPK && t >= total) {
            float* o = orow + t * 5;
            o[0] = 0.f; o[1] = 0.f; o[2] = 0.f; o[3] = 0.f; o[4] = 0.f;
        }
    }
}

extern "C" void kernel_launch(void* const* d_in, const int* in_sizes, int n_in,
                              void* d_out, int out_size, void* d_ws, size_t ws_size,
                              hipStream_t stream) {
    const float* loc = (const float*)d_in[0];
    const float* conf = (const float*)d_in[1];
    const float* prior = (const float*)d_in[2];
    float* out = (float*)d_out;

    int P = in_sizes[2] / 4;                // 8732
    int B = in_sizes[0] / (4 * P);          // 32

    // ws layout: msum float2[B*P] at 0 (2.24 MB); barrier word at +4 MB
    // (ws_size >= 22.35 MB from earlier rounds; regions disjoint by miles)
    float2* msum = (float2*)d_ws;
    unsigned int* bar = (unsigned int*)((char*)d_ws + (4u << 20));

    hipMemsetAsync((void*)bar, 0, 64, stream);   // zero the barrier counter

    int nblk = B * NFG;
    fused_nms_kernel<<<nblk, BS, 0, stream>>>(conf, loc, prior, out,
                                              msum, bar, B, P, nblk);
}